// Round 8
// baseline (183.580 us; speedup 1.0000x reference)
//
#include <hip/hip_runtime.h>

#define DIM   128
#define HALF  64          // columns per slice (2 slices, XCD-parity L2 residency)
#define CPT   256         // chars per wave-chunk
#define TAIL  64          // staged lookahead for cross-chunk tails
#define WPB   4           // waves per block

// Streaming loads marked non-temporal so they don't evict char_emb from L2.
#define NTL(p) __builtin_nontemporal_load(p)
typedef float f4v __attribute__((ext_vector_type(4)));   // NT-loadable float4

// out = N - <H,T>_F / (||H||_F ||T||_F).  T never materialized.
// Round-6 structure (ties best dur 79-80us, lowest FETCH 53MB): 2-slice
// XCD-parity, depth-2 PF, chained boundary hv load, hh folded at boundary
// events, gap/lead/trail empties handled in mask phase + reduce kernel.
// ONE delta vs round 6: all *streaming* traffic (ids, seg ids, ent-row
// gathers) is loaded non-temporally. Theory: those streams (~77MB/launch)
// were continuously evicting the 2.56MB char_emb slice from the 4MB XCD L2,
// pushing the 819MB of char gathers out to Infinity-Cache latency
// (~500-900cy) -- the measured ~90% wave-stall. With nt on the streams,
// char gathers become real L2 hits (~200cy).
__global__ __launch_bounds__(256) void fused_kernel(
    const float* __restrict__ char_emb,
    const float* __restrict__ ent,
    const int* __restrict__ head_ids,
    const int* __restrict__ char_ids,
    const int* __restrict__ seg_ids,
    float* __restrict__ pb,        // [gridDim.x*3] block partials: ht,tt,hh
    int total_chars)
{
    __shared__ __align__(16) int s_off[WPB][CPT + TAIL];  // (cid<<9)+sco
    __shared__ int s_sid[WPB][CPT + TAIL];
    __shared__ float r_scr[3][WPB];

    const int tid  = threadIdx.x;
    const int lane = tid & 63;
    const int wid  = tid >> 6;
    const int colb = lane << 2;               // byte offset of lane's column

    float ht = 0.f, tt = 0.f, hh = 0.f;

    const int slice = blockIdx.x & 1;         // XCD-parity slice mapping
    const int sco   = slice << 8;             // slice*64 cols*4B
    const int chunk = (blockIdx.x >> 1) * WPB + wid;
    const int start = chunk * CPT;
    const int len   = min(CPT, total_chars - start);
    const int sl    = min(CPT + TAIL, total_chars - start);
    const char* cb  = (const char*)char_emb;
    const float* ee = ent + slice * HALF + lane;

    // ---- stage offsets + sids (wave-local region; nt streaming reads) ----
    for (int c = lane; c < sl; c += 64) {
        s_off[wid][c] = (NTL(&char_ids[start + c]) << 9) + sco;
        s_sid[wid][c] = NTL(&seg_ids[start + c]);
    }
    // ---- boundary masks, kept in SGPRs (ballot is wave-uniform) ----
    unsigned long long mk[4] = {0ull, 0ull, 0ull, 0ull};
    if (len == CPT) {
#pragma unroll
        for (int grp = 0; grp < 4; ++grp) {
            const int c = start + grp * 64 + lane;
            const int s1 = NTL(&seg_ids[c]);
            const int s0 = (c > 0) ? NTL(&seg_ids[c - 1]) : (s1 + 1); // char 0: bnd
            mk[grp] = __ballot(s1 != s0);
            // empty triples between s0 and s1: statistically never taken
            unsigned long long gapm = __ballot(s1 > s0 + 1);
            while (gapm) {
                const int l  = __ffsll((long long)gapm) - 1;
                const int g0 = __shfl(s0, l);
                const int g1 = __shfl(s1, l);
                for (int g = g0 + 1; g < g1; ++g) {
                    const float gv = NTL(&ee[(size_t)head_ids[g] * DIM]);
                    hh = fmaf(gv, gv, hh);
                }
                gapm &= gapm - 1;
            }
        }
    }
    __syncthreads();

    if (len == CPT) {
        // -------- fast path --------
        int cur = __builtin_amdgcn_readfirstlane(s_sid[wid][0]);
        float hv = NTL(&ee[(size_t)head_ids[cur] * DIM]);  // prefetched head row
        float acc = 0.f;
        bool live = false;      // first flush dropped iff chunk starts mid-segment
        float vA[16], vB[16];

#define PF(BUF, B) { \
    _Pragma("unroll") \
    for (int q = 0; q < 4; ++q) { \
        const int4 o4 = *(const int4*)&s_off[wid][(B) * 16 + q * 4]; \
        BUF[q * 4 + 0] = *(const float*)(cb + (size_t)(unsigned)(o4.x + colb)); \
        BUF[q * 4 + 1] = *(const float*)(cb + (size_t)(unsigned)(o4.y + colb)); \
        BUF[q * 4 + 2] = *(const float*)(cb + (size_t)(unsigned)(o4.z + colb)); \
        BUF[q * 4 + 3] = *(const float*)(cb + (size_t)(unsigned)(o4.w + colb)); \
    } }

#define CS(BUF, B) { \
    _Pragma("unroll") \
    for (int j = 0; j < 16; ++j) { \
        if (mk[(B) >> 2] & (1ull << (((B) & 3) * 16 + j))) {   /* scalar bit test */ \
            if (live) { ht = fmaf(hv, acc, ht); tt = fmaf(acc, acc, tt); } \
            live = true; \
            acc = 0.f; \
            cur = __builtin_amdgcn_readfirstlane(s_sid[wid][(B) * 16 + j]); \
            hv = NTL(&ee[(size_t)head_ids[cur] * DIM]);  /* s_load id + nt row */ \
            hh = fmaf(hv, hv, hh);                   /* boundary event: ||h||^2 */ \
        } \
        acc += BUF[j]; \
    } }

        PF(vA, 0)
#pragma unroll
        for (int B = 0; B < 16; ++B) {
            if (B + 1 < 16) { if (B & 1) { PF(vA, B + 1) } else { PF(vB, B + 1) } }
            if (B & 1) { CS(vB, B) } else { CS(vA, B) }
        }

        if (live) {
            // tail: last owned segment may continue past chunk end
            int e = CPT;
            bool ended = false;
            while (e < sl) {
                const int idx = e + lane;
                const bool differ = (idx < sl) && (s_sid[wid][idx] != cur);
                const unsigned long long bm = __ballot(differ);
                const int run = bm ? (__ffsll((long long)bm) - 1)
                                   : min(64, sl - e);
                for (int j = 0; j < run; j += 4) {
                    const int mm2 = min(4, run - j);
                    float vv[4];
#pragma unroll
                    for (int k = 0; k < 4; ++k) {
                        if (k < mm2)
                            vv[k] = *(const float*)(cb +
                                (size_t)(unsigned)(s_off[wid][e + j + k] + colb));
                    }
                    for (int k = 0; k < mm2; ++k) acc += vv[k];
                }
                e += run;
                if (bm) { ended = true; break; }
            }
            if (!ended && start + sl < total_chars) {
                int gg = start + sl;                 // very rare long run
                while (gg < total_chars && NTL(&seg_ids[gg]) == cur) {
                    acc += *(const float*)(cb +
                        (size_t)(unsigned)((NTL(&char_ids[gg]) << 9) + sco + colb));
                    ++gg;
                }
            }
            // final flush
            ht = fmaf(hv, acc, ht);
            tt = fmaf(acc, acc, tt);
        }
    } else if (len > 0) {
        // -------- rare fallback (partial last chunk): scalar per char --------
        const float* cembF = char_emb + slice * HALF + lane;
        int p = 0;
        if (start > 0) {
            const int prev = NTL(&seg_ids[start - 1]);
            while (p < len && NTL(&seg_ids[start + p]) == prev) ++p;
        }
        if (p < len) {
            int cur2 = NTL(&seg_ids[start + p]);
            if (start > 0) {                     // gap before first owned segment
                for (int g = NTL(&seg_ids[start - 1]) + 1; g < cur2; ++g) {
                    const float gv = NTL(&ee[(size_t)head_ids[g] * DIM]);
                    hh = fmaf(gv, gv, hh);
                }
            }
            float acc = 0.f;
            float hv = NTL(&ee[(size_t)head_ids[cur2] * DIM]);
            hh = fmaf(hv, hv, hh);
            for (int c = p; c < len; ++c) {
                const int sid = NTL(&seg_ids[start + c]);
                if (sid != cur2) {
                    ht += hv * acc; tt += acc * acc;
                    for (int g = cur2 + 1; g < sid; ++g) {   // interior gaps
                        const float gv = NTL(&ee[(size_t)head_ids[g] * DIM]);
                        hh = fmaf(gv, gv, hh);
                    }
                    acc = 0.f; cur2 = sid;
                    hv = NTL(&ee[(size_t)head_ids[cur2] * DIM]);
                    hh = fmaf(hv, hv, hh);
                }
                acc += cembF[(size_t)char_ids[start + c] * DIM];
            }
            int gg = start + len;
            while (gg < total_chars && NTL(&seg_ids[gg]) == cur2) {
                acc += cembF[(size_t)char_ids[gg] * DIM];
                ++gg;
            }
            ht += hv * acc; tt += acc * acc;
        }
    }

    // -------- block reduce -> per-block partials (no atomics, no memset) ----
#pragma unroll
    for (int off = 32; off > 0; off >>= 1) {
        ht += __shfl_down(ht, off);
        tt += __shfl_down(tt, off);
        hh += __shfl_down(hh, off);
    }
    if (lane == 0) { r_scr[0][wid] = ht; r_scr[1][wid] = tt; r_scr[2][wid] = hh; }
    __syncthreads();
    if (tid == 0) {
        float a = 0.f, b = 0.f, c = 0.f;
#pragma unroll
        for (int w = 0; w < WPB; ++w) {
            a += r_scr[0][w]; b += r_scr[1][w]; c += r_scr[2][w];
        }
        pb[blockIdx.x * 3 + 0] = a;
        pb[blockIdx.x * 3 + 1] = b;
        pb[blockIdx.x * 3 + 2] = c;
    }
}

// final reduce: sums partials in double, adds hh for leading/trailing empty
// triples (rows with no chars before the first / after the last seg id),
// writes N - ht/sqrt(hh*tt)
__global__ __launch_bounds__(256) void reduce_kernel(
    const float* __restrict__ pb, int nb, float* __restrict__ out,
    int n_triples, const int* __restrict__ seg_ids,
    const int* __restrict__ head_ids, const float* __restrict__ ent,
    int total_chars)
{
    double ht = 0.0, tt = 0.0, hh = 0.0;
    for (int i = threadIdx.x; i < nb; i += 256) {
        ht += (double)pb[i * 3 + 0];
        tt += (double)pb[i * 3 + 1];
        hh += (double)pb[i * 3 + 2];
    }
    // leading/trailing empty triples (typically 0)
    int first = n_triples, last = n_triples - 1;
    if (total_chars > 0) { first = seg_ids[0]; last = seg_ids[total_chars - 1]; }
    const int lead  = first;
    const int trail = n_triples - 1 - last;
    const int tot   = lead + trail;
    const f4v* e4 = (const f4v*)ent;
    for (int w = threadIdx.x; w < tot * 32; w += 256) {
        const int rr = w >> 5;
        const int g  = (rr < lead) ? rr : (last + 1 + (rr - lead));
        const f4v v = NTL(&e4[(size_t)head_ids[g] * 32 + (w & 31)]);
        hh += (double)v.x * v.x + (double)v.y * v.y
            + (double)v.z * v.z + (double)v.w * v.w;
    }
#pragma unroll
    for (int off = 32; off > 0; off >>= 1) {
        ht += __shfl_down(ht, off);
        tt += __shfl_down(tt, off);
        hh += __shfl_down(hh, off);
    }
    __shared__ double sd[3][4];
    const int wid = threadIdx.x >> 6;
    if ((threadIdx.x & 63) == 0) { sd[0][wid] = ht; sd[1][wid] = tt; sd[2][wid] = hh; }
    __syncthreads();
    if (threadIdx.x == 0) {
        double a = 0.0, b = 0.0, c = 0.0;
        for (int w = 0; w < 4; ++w) { a += sd[0][w]; b += sd[1][w]; c += sd[2][w]; }
        out[0] = (float)((double)n_triples - a / sqrt(c * b));
    }
}

extern "C" void kernel_launch(void* const* d_in, const int* in_sizes, int n_in,
                              void* d_out, int out_size, void* d_ws, size_t ws_size,
                              hipStream_t stream)
{
    const float* char_emb = (const float*)d_in[0];
    const float* ent_emb  = (const float*)d_in[1];
    const int* head_ids   = (const int*)d_in[2];
    const int* char_ids   = (const int*)d_in[3];
    const int* seg_ids    = (const int*)d_in[4];
    const int n_triples   = in_sizes[2];
    const int total_chars = in_sizes[3];

    const int n_chunks = (total_chars + CPT - 1) / CPT;
    const int bps = (n_chunks + WPB - 1) / WPB;
    const int nsb = (2 * bps > 0) ? 2 * bps : 2;   // x2 slices

    float* pb = (float*)d_ws;                      // nsb*3 floats

    fused_kernel<<<nsb, 256, 0, stream>>>(char_emb, ent_emb, head_ids,
                                          char_ids, seg_ids, pb,
                                          total_chars);
    reduce_kernel<<<1, 256, 0, stream>>>(pb, nsb, (float*)d_out, n_triples,
                                         seg_ids, head_ids, ent_emb,
                                         total_chars);
}